// Round 9
// baseline (75.785 us; speedup 1.0000x reference)
//
#include <hip/hip_runtime.h>
#include <hip/hip_bf16.h>
#include <math.h>

#define DD 256      // feature dim
#define SS 1024     // seq len
#define BB 8        // batch
#define NN 128      // nodes
#define KC 64       // k-chunk for fallback scorer
#define PNT 16      // nodes per pool block
#define PSC 16      // S-chunks in pool
#define PSCH (SS/PSC)  // 64

typedef __attribute__((ext_vector_type(8))) short short8;
typedef __attribute__((ext_vector_type(4))) float f32x4;

__device__ __forceinline__ unsigned short f2bf(float x) {
    unsigned u = __builtin_bit_cast(unsigned, x);
    u += 0x7fffu + ((u >> 16) & 1u);          // round-to-nearest-even
    return (unsigned short)(u >> 16);
}
__device__ __forceinline__ float bf2f(unsigned short h) {
    return __builtin_bit_cast(float, (unsigned)h << 16);
}

// ============ Kernel 0a: doc -> hi/lo split (elementwise, no transpose) ============
__global__ __launch_bounds__(256) void split_doc_kernel(
    const float* __restrict__ doc,
    unsigned short* __restrict__ doc_hi, unsigned short* __restrict__ doc_lo)
{
    const int idx = blockIdx.x * 256 + threadIdx.x;   // 131072 threads
    const float4* in4 = reinterpret_cast<const float4*>(doc);
    ushort4* h4 = reinterpret_cast<ushort4*>(doc_hi);
    ushort4* l4 = reinterpret_cast<ushort4*>(doc_lo);
#pragma unroll
    for (int r = 0; r < 4; ++r) {
        const int i = idx + r * 131072;               // 524288 float4 total
        const float4 v = in4[i];
        ushort4 h, l;
        h.x = f2bf(v.x); l.x = f2bf(v.x - bf2f(h.x));
        h.y = f2bf(v.y); l.y = f2bf(v.y - bf2f(h.y));
        h.z = f2bf(v.z); l.z = f2bf(v.z - bf2f(h.z));
        h.w = f2bf(v.w); l.w = f2bf(v.w - bf2f(h.w));
        h4[i] = h; l4[i] = l;
    }
}

// ============ Kernel 0b: W1 -> W1T hi/lo (transposed, 64x64 LDS tiles) ============
__global__ __launch_bounds__(256) void split_w1t_kernel(
    const float* __restrict__ W1,
    unsigned short* __restrict__ w1t_hi, unsigned short* __restrict__ w1t_lo)
{
    __shared__ float tl[64][65];
    const int tid = threadIdx.x;
    const int k0 = (blockIdx.x >> 2) * 64, n0 = (blockIdx.x & 3) * 64;
#pragma unroll
    for (int i = 0; i < 16; ++i) {
        const int idx = i * 256 + tid;
        const int r = idx >> 6, c = idx & 63;
        tl[r][c] = W1[(size_t)(k0 + r) * DD + n0 + c];
    }
    __syncthreads();
#pragma unroll
    for (int i = 0; i < 16; ++i) {
        const int idx = i * 256 + tid;
        const int nl = idx >> 6, kl = idx & 63;
        const float v = tl[kl][nl];
        const unsigned short h = f2bf(v);
        const size_t o = (size_t)(n0 + nl) * DD + k0 + kl;
        w1t_hi[o] = h;
        w1t_lo[o] = f2bf(v - bf2f(h));
    }
}

// ============ Kernel 1: MFMA scorer GEMM h = doc @ W1 (split-bf16 x3) ============
// grid 512: token-tile (blk>>2, 64 tokens) x col-tile (blk&3, 64 cols).
// 4 waves; wave owns 16 tokens x 64 cols (4 16x16 C tiles). K=256 -> 8 ksteps.
__global__ __launch_bounds__(256) void scorer_mfma_kernel(
    const unsigned short* __restrict__ doc_hi, const unsigned short* __restrict__ doc_lo,
    const unsigned short* __restrict__ w1t_hi, const unsigned short* __restrict__ w1t_lo,
    float* __restrict__ hbuf)
{
    const int tid  = threadIdx.x;
    const int wave = tid >> 6, lane = tid & 63;
    const int l15  = lane & 15, kg = lane >> 4;
    const int t0 = (blockIdx.x >> 2) * 64 + wave * 16;
    const int n0 = (blockIdx.x & 3) * 64;

    const f32x4 z = {0.f, 0.f, 0.f, 0.f};
    f32x4 acc[4] = {z, z, z, z};

    const size_t arow = (size_t)(t0 + l15) * DD;
#pragma unroll 2
    for (int ks = 0; ks < 8; ++ks) {
        const int k = ks * 32 + kg * 8;
        const short8 ah = *reinterpret_cast<const short8*>(doc_hi + arow + k);
        const short8 al = *reinterpret_cast<const short8*>(doc_lo + arow + k);
#pragma unroll
        for (int nt = 0; nt < 4; ++nt) {
            const size_t brow = (size_t)(n0 + nt * 16 + l15) * DD;
            const short8 bh = *reinterpret_cast<const short8*>(w1t_hi + brow + k);
            const short8 bl = *reinterpret_cast<const short8*>(w1t_lo + brow + k);
            acc[nt] = __builtin_amdgcn_mfma_f32_16x16x32_bf16(ah, bh, acc[nt], 0, 0, 0);
            acc[nt] = __builtin_amdgcn_mfma_f32_16x16x32_bf16(ah, bl, acc[nt], 0, 0, 0);
            acc[nt] = __builtin_amdgcn_mfma_f32_16x16x32_bf16(al, bh, acc[nt], 0, 0, 0);
        }
    }
    // C/D layout: col = lane&15, row = (lane>>4)*4 + reg  [m89-verified]
#pragma unroll
    for (int nt = 0; nt < 4; ++nt)
#pragma unroll
        for (int r = 0; r < 4; ++r)
            hbuf[(size_t)(t0 + kg * 4 + r) * DD + n0 + nt * 16 + l15] = acc[nt][r];
}

// ============ Kernel 2: combine = +b1, LN, GELU, @W2 -> scores ============
__global__ __launch_bounds__(256) void combine_kernel(
    const float* __restrict__ hbuf, const float* __restrict__ b1,
    const float* __restrict__ gamma, const float* __restrict__ beta,
    const float* __restrict__ W2, const float* __restrict__ b2,
    float* __restrict__ scores)
{
    const int tid  = threadIdx.x;
    const int wave = tid >> 6, lane = tid & 63;
    const int t0   = blockIdx.x * 16;
    const int c0   = lane * 4;

    const float4 bv  = *reinterpret_cast<const float4*>(b1 + c0);
    const float4 gm  = *reinterpret_cast<const float4*>(gamma + c0);
    const float4 be  = *reinterpret_cast<const float4*>(beta + c0);
    const float4 w2v = *reinterpret_cast<const float4*>(W2 + c0);
    const float  b2v = b2[0];

#pragma unroll
    for (int t = 0; t < 4; ++t) {
        const int row = t0 + wave * 4 + t;
        float4 h = *reinterpret_cast<const float4*>(hbuf + (size_t)row * DD + c0);
        h.x += bv.x; h.y += bv.y; h.z += bv.z; h.w += bv.w;

        float s1 = h.x + h.y + h.z + h.w;
        float s2 = h.x * h.x + h.y * h.y + h.z * h.z + h.w * h.w;
#pragma unroll
        for (int off = 32; off > 0; off >>= 1) {
            s1 += __shfl_xor(s1, off, 64);
            s2 += __shfl_xor(s2, off, 64);
        }
        const float mean = s1 * (1.f / DD);
        const float var  = s2 * (1.f / DD) - mean * mean;
        const float inv  = rsqrtf(var + 1e-5f);

        const float n0 = (h.x - mean) * inv * gm.x + be.x;
        const float n1 = (h.y - mean) * inv * gm.y + be.y;
        const float n2 = (h.z - mean) * inv * gm.z + be.z;
        const float n3 = (h.w - mean) * inv * gm.w + be.w;
        const float kq = 0.70710678118654752f;
        const float g0 = 0.5f * n0 * (1.f + erff(n0 * kq));
        const float g1 = 0.5f * n1 * (1.f + erff(n1 * kq));
        const float g2 = 0.5f * n2 * (1.f + erff(n2 * kq));
        const float g3 = 0.5f * n3 * (1.f + erff(n3 * kq));
        float sc = g0 * w2v.x + g1 * w2v.y + g2 * w2v.z + g3 * w2v.w;
#pragma unroll
        for (int off = 32; off > 0; off >>= 1) sc += __shfl_xor(sc, off, 64);
        if (lane == 0) scores[row] = sc + b2v;
    }
}

// ====== Kernel 3 (r7 verbatim, PASSED): masked softmax -> float weights w ======
__global__ __launch_bounds__(256) void statsw_kernel(
    const float* __restrict__ mapping, const float* __restrict__ scores,
    float* __restrict__ w)
{
    __shared__ float sc_s[SS];
    const int tid  = threadIdx.x, lane = tid & 63;
    const int wave = __builtin_amdgcn_readfirstlane(tid >> 6);
    const int g0   = blockIdx.x * 4;
    const int b    = g0 >> 7;

    reinterpret_cast<float4*>(sc_s)[tid] =
        reinterpret_cast<const float4*>(scores + (size_t)b * SS)[tid];
    __syncthreads();

    const int g = g0 + wave;
    const float4* mrow4 = reinterpret_cast<const float4*>(mapping + (size_t)g * SS);
    const float4* sc4   = reinterpret_cast<const float4*>(sc_s);

    float4 mv[4], sv[4];
    float mx = -INFINITY;
#pragma unroll
    for (int q = 0; q < 4; ++q) {
        mv[q] = mrow4[lane + (q << 6)];
        sv[q] = sc4[lane + (q << 6)];
        if (mv[q].x > 0.5f) mx = fmaxf(mx, sv[q].x);
        if (mv[q].y > 0.5f) mx = fmaxf(mx, sv[q].y);
        if (mv[q].z > 0.5f) mx = fmaxf(mx, sv[q].z);
        if (mv[q].w > 0.5f) mx = fmaxf(mx, sv[q].w);
    }
#pragma unroll
    for (int off = 32; off > 0; off >>= 1) mx = fmaxf(mx, __shfl_xor(mx, off, 64));
    float z = 0.f;
    float4 ev[4];
#pragma unroll
    for (int q = 0; q < 4; ++q) {
        ev[q].x = (mv[q].x > 0.5f) ? __expf(sv[q].x - mx) : 0.f;
        ev[q].y = (mv[q].y > 0.5f) ? __expf(sv[q].y - mx) : 0.f;
        ev[q].z = (mv[q].z > 0.5f) ? __expf(sv[q].z - mx) : 0.f;
        ev[q].w = (mv[q].w > 0.5f) ? __expf(sv[q].w - mx) : 0.f;
        z += ev[q].x + ev[q].y + ev[q].z + ev[q].w;
    }
#pragma unroll
    for (int off = 32; off > 0; off >>= 1) z += __shfl_xor(z, off, 64);
    const float invz = (z > 0.f) ? (1.f / z) : 0.f;

    float4* wrow4 = reinterpret_cast<float4*>(w + (size_t)g * SS);
#pragma unroll
    for (int q = 0; q < 4; ++q) {
        float4 e;
        e.x = ev[q].x * invz; e.y = ev[q].y * invz;
        e.z = ev[q].z * invz; e.w = ev[q].w * invz;
        wrow4[lane + (q << 6)] = e;
    }
}

// ====== Kernel 4 (r7 verbatim, PASSED): pooled partials, scalar-load weights ======
__global__ __launch_bounds__(256) void pool16_kernel(
    const float* __restrict__ doc, const float* __restrict__ w,
    float* __restrict__ part)
{
    const int blk = blockIdx.x;
    const int c   = blk & (PSC - 1);
    const int nt  = (blk >> 4) & 7;
    const int b   = blk >> 7;
    const int s0  = c * PSCH;
    const int d   = threadIdx.x;

    float acc[PNT];
#pragma unroll
    for (int n = 0; n < PNT; ++n) acc[n] = 0.f;

    const float* docb = doc + ((size_t)b * SS + s0) * DD;
    const float* wb   = w + ((size_t)(b * NN + nt * PNT)) * SS + s0;

#pragma unroll 1
    for (int sb = 0; sb < PSCH; sb += 16) {
        float dr[16];
#pragma unroll
        for (int j = 0; j < 16; ++j)
            dr[j] = docb[(size_t)(sb + j) * DD + d];

#pragma unroll
        for (int n = 0; n < PNT; ++n) {
            const float* wn = wb + (size_t)n * SS + sb;
            const float4 w0 = *reinterpret_cast<const float4*>(wn);
            const float4 w1 = *reinterpret_cast<const float4*>(wn + 4);
            const float4 w2 = *reinterpret_cast<const float4*>(wn + 8);
            const float4 w3 = *reinterpret_cast<const float4*>(wn + 12);
            float a = acc[n];
            a = fmaf(w0.x, dr[0],  a);
            a = fmaf(w0.y, dr[1],  a);
            a = fmaf(w0.z, dr[2],  a);
            a = fmaf(w0.w, dr[3],  a);
            a = fmaf(w1.x, dr[4],  a);
            a = fmaf(w1.y, dr[5],  a);
            a = fmaf(w1.z, dr[6],  a);
            a = fmaf(w1.w, dr[7],  a);
            a = fmaf(w2.x, dr[8],  a);
            a = fmaf(w2.y, dr[9],  a);
            a = fmaf(w2.z, dr[10], a);
            a = fmaf(w2.w, dr[11], a);
            a = fmaf(w3.x, dr[12], a);
            a = fmaf(w3.y, dr[13], a);
            a = fmaf(w3.z, dr[14], a);
            a = fmaf(w3.w, dr[15], a);
            acc[n] = a;
        }
    }

    float* p = part + (size_t)blk * (PNT * DD);
#pragma unroll
    for (int n = 0; n < PNT; ++n) p[(size_t)n * DD + d] = acc[n];
}

// ---------------- Kernel 5 (r7 verbatim, PASSED): reduce PSC partials ----------------
__global__ __launch_bounds__(256) void reduce16_kernel(
    const float* __restrict__ part, float* __restrict__ out)
{
    const int o = blockIdx.x * 256 + threadIdx.x;
    const int d = o & 255;
    const int g = o >> 8;
    const int b = g >> 7;
    const int n = g & 127;
    const int nt = n >> 4, nl = n & 15;
    const size_t base = ((size_t)(b * 128 + nt * 16)) * (PNT * DD)
                      + (size_t)nl * DD + d;
    float s = 0.f;
#pragma unroll
    for (int c = 0; c < PSC; ++c) s += part[base + (size_t)c * (PNT * DD)];
    out[o] = s;
}

// ================= Fallback path (tiny ws): r5 verified kernels =================
__global__ __launch_bounds__(256) void scorer_kernel(
    const float* __restrict__ doc, const float* __restrict__ W1,
    const float* __restrict__ b1, const float* __restrict__ gamma,
    const float* __restrict__ beta, const float* __restrict__ W2,
    const float* __restrict__ b2, float* __restrict__ scores)
{
    __shared__ float xs[16][DD];
    __shared__ float w1s[KC][DD];

    const int tid  = threadIdx.x;
    const int wave = tid >> 6, lane = tid & 63;
    const int t0   = blockIdx.x * 16;
    const int c0   = lane * 4;

    {
        const float4* src = reinterpret_cast<const float4*>(doc + (size_t)t0 * DD);
        float4* dst = reinterpret_cast<float4*>(&xs[0][0]);
#pragma unroll
        for (int r = 0; r < 4; ++r) dst[tid + 256 * r] = src[tid + 256 * r];
    }

    float4 acc[4];
    {
        const float4 bv = *reinterpret_cast<const float4*>(b1 + c0);
#pragma unroll
        for (int t = 0; t < 4; ++t) acc[t] = bv;
    }
    const float* xw = &xs[wave * 4][0];

    for (int kc = 0; kc < DD / KC; ++kc) {
        __syncthreads();
        {
            const float4* wsrc = reinterpret_cast<const float4*>(W1 + (size_t)kc * KC * DD);
            float4* wdst = reinterpret_cast<float4*>(&w1s[0][0]);
#pragma unroll
            for (int r = 0; r < 16; ++r) wdst[tid + 256 * r] = wsrc[tid + 256 * r];
        }
        __syncthreads();
#pragma unroll 4
        for (int k4 = 0; k4 < KC / 4; ++k4) {
            const int kb = k4 * 4;
            const float4 w0 = *reinterpret_cast<const float4*>(&w1s[kb + 0][c0]);
            const float4 w1 = *reinterpret_cast<const float4*>(&w1s[kb + 1][c0]);
            const float4 w2 = *reinterpret_cast<const float4*>(&w1s[kb + 2][c0]);
            const float4 w3 = *reinterpret_cast<const float4*>(&w1s[kb + 3][c0]);
#pragma unroll
            for (int t = 0; t < 4; ++t) {
                const float4 xv = *reinterpret_cast<const float4*>(xw + (size_t)t * DD + kc * KC + kb);
                acc[t].x = fmaf(xv.x, w0.x, acc[t].x);
                acc[t].y = fmaf(xv.x, w0.y, acc[t].y);
                acc[t].z = fmaf(xv.x, w0.z, acc[t].z);
                acc[t].w = fmaf(xv.x, w0.w, acc[t].w);
                acc[t].x = fmaf(xv.y, w1.x, acc[t].x);
                acc[t].y = fmaf(xv.y, w1.y, acc[t].y);
                acc[t].z = fmaf(xv.y, w1.z, acc[t].z);
                acc[t].w = fmaf(xv.y, w1.w, acc[t].w);
                acc[t].x = fmaf(xv.z, w2.x, acc[t].x);
                acc[t].y = fmaf(xv.z, w2.y, acc[t].y);
                acc[t].z = fmaf(xv.z, w2.z, acc[t].z);
                acc[t].w = fmaf(xv.z, w2.w, acc[t].w);
                acc[t].x = fmaf(xv.w, w3.x, acc[t].x);
                acc[t].y = fmaf(xv.w, w3.y, acc[t].y);
                acc[t].z = fmaf(xv.w, w3.z, acc[t].z);
                acc[t].w = fmaf(xv.w, w3.w, acc[t].w);
            }
        }
    }

    const float4 gm = *reinterpret_cast<const float4*>(gamma + c0);
    const float4 be = *reinterpret_cast<const float4*>(beta + c0);
    const float4 w2v = *reinterpret_cast<const float4*>(W2 + c0);
    const float b2v = b2[0];

#pragma unroll
    for (int t = 0; t < 4; ++t) {
        float s1 = acc[t].x + acc[t].y + acc[t].z + acc[t].w;
        float s2 = acc[t].x * acc[t].x + acc[t].y * acc[t].y
                 + acc[t].z * acc[t].z + acc[t].w * acc[t].w;
#pragma unroll
        for (int off = 32; off > 0; off >>= 1) {
            s1 += __shfl_xor(s1, off, 64);
            s2 += __shfl_xor(s2, off, 64);
        }
        const float mean = s1 * (1.f / DD);
        const float var  = s2 * (1.f / DD) - mean * mean;
        const float inv  = rsqrtf(var + 1e-5f);
        float n0 = (acc[t].x - mean) * inv * gm.x + be.x;
        float n1 = (acc[t].y - mean) * inv * gm.y + be.y;
        float n2 = (acc[t].z - mean) * inv * gm.z + be.z;
        float n3 = (acc[t].w - mean) * inv * gm.w + be.w;
        const float kq = 0.70710678118654752f;
        float g0 = 0.5f * n0 * (1.f + erff(n0 * kq));
        float g1 = 0.5f * n1 * (1.f + erff(n1 * kq));
        float g2 = 0.5f * n2 * (1.f + erff(n2 * kq));
        float g3 = 0.5f * n3 * (1.f + erff(n3 * kq));
        float sc = g0 * w2v.x + g1 * w2v.y + g2 * w2v.z + g3 * w2v.w;
#pragma unroll
        for (int off = 32; off > 0; off >>= 1) sc += __shfl_xor(sc, off, 64);
        if (lane == 0) scores[t0 + wave * 4 + t] = sc + b2v;
    }
}

__global__ __launch_bounds__(256) void stats_kernel(
    const float* __restrict__ mapping, const float* __restrict__ scores,
    float* __restrict__ mx_out, float* __restrict__ invz_out)
{
    __shared__ float sc_s[SS];
    const int tid = threadIdx.x, wave = tid >> 6, lane = tid & 63;
    const int g0 = blockIdx.x * 4;
    const int b  = g0 >> 7;

    reinterpret_cast<float4*>(sc_s)[tid] =
        reinterpret_cast<const float4*>(scores + (size_t)b * SS)[tid];
    __syncthreads();

    const int g = g0 + wave;
    const float4* mrow4 = reinterpret_cast<const float4*>(mapping + (size_t)g * SS);
    const float4* sc4   = reinterpret_cast<const float4*>(sc_s);

    float4 mv[4], sv[4];
    float mx = -INFINITY;
#pragma unroll
    for (int q = 0; q < 4; ++q) {
        mv[q] = mrow4[lane + (q << 6)];
        sv[q] = sc4[lane + (q << 6)];
        if (mv[q].x > 0.5f) mx = fmaxf(mx, sv[q].x);
        if (mv[q].y > 0.5f) mx = fmaxf(mx, sv[q].y);
        if (mv[q].z > 0.5f) mx = fmaxf(mx, sv[q].z);
        if (mv[q].w > 0.5f) mx = fmaxf(mx, sv[q].w);
    }
#pragma unroll
    for (int off = 32; off > 0; off >>= 1) mx = fmaxf(mx, __shfl_xor(mx, off, 64));
    float z = 0.f;
#pragma unroll
    for (int q = 0; q < 4; ++q) {
        if (mv[q].x > 0.5f) z += __expf(sv[q].x - mx);
        if (mv[q].y > 0.5f) z += __expf(sv[q].y - mx);
        if (mv[q].z > 0.5f) z += __expf(sv[q].z - mx);
        if (mv[q].w > 0.5f) z += __expf(sv[q].w - mx);
    }
#pragma unroll
    for (int off = 32; off > 0; off >>= 1) z += __shfl_xor(z, off, 64);
    if (lane == 0) {
        mx_out[g]   = mx;
        invz_out[g] = (z > 0.f) ? (1.f / z) : 0.f;
    }
}

__global__ __launch_bounds__(256) void pool_direct_kernel(
    const float* __restrict__ doc, const float* __restrict__ mapping,
    const float* __restrict__ scores, const float* __restrict__ mx_in,
    const float* __restrict__ invz_in, float* __restrict__ out)
{
    __shared__ float w_lds[8][SS];

    const int bt    = blockIdx.x;
    const int ntile = bt & 15;
    const int b     = bt >> 4;
    const int tid = threadIdx.x, wave = tid >> 6, lane = tid & 63;

    {
        const int nl = wave * 2 + (lane >> 5);
        const int g  = b * NN + ntile * 8 + nl;
        const float mx   = mx_in[g];
        const float invz = invz_in[g];
        const float4* mrow4 = reinterpret_cast<const float4*>(mapping + (size_t)g * SS);
        const float4* srow4 = reinterpret_cast<const float4*>(scores + (size_t)b * SS);
        float4* wrow4 = reinterpret_cast<float4*>(&w_lds[nl][0]);
        const int idx0 = lane & 31;
#pragma unroll
        for (int q = 0; q < SS / 128; ++q) {
            const int idx = idx0 + 32 * q;
            const float4 mp = mrow4[idx];
            const float4 sv = srow4[idx];
            float4 e;
            e.x = (mp.x > 0.5f) ? __expf(sv.x - mx) * invz : 0.f;
            e.y = (mp.y > 0.5f) ? __expf(sv.y - mx) * invz : 0.f;
            e.z = (mp.z > 0.5f) ? __expf(sv.z - mx) * invz : 0.f;
            e.w = (mp.w > 0.5f) ? __expf(sv.w - mx) * invz : 0.f;
            wrow4[idx] = e;
        }
    }
    __syncthreads();

    float acc[8];
#pragma unroll
    for (int n = 0; n < 8; ++n) acc[n] = 0.f;
    const float* docb = doc + (size_t)b * SS * DD;

    for (int s4 = 0; s4 < SS; s4 += 4) {
        const float d0 = docb[(size_t)(s4 + 0) * DD + tid];
        const float d1 = docb[(size_t)(s4 + 1) * DD + tid];
        const float d2 = docb[(size_t)(s4 + 2) * DD + tid];
        const float d3 = docb[(size_t)(s4 + 3) * DD + tid];
#pragma unroll
        for (int n = 0; n < 8; ++n) {
            const float4 wv = *reinterpret_cast<const float4*>(&w_lds[n][s4]);
            acc[n] = fmaf(wv.x, d0, acc[n]);
            acc[n] = fmaf(wv.y, d1, acc[n]);
            acc[n] = fmaf(wv.z, d2, acc[n]);
            acc[n] = fmaf(wv.w, d3, acc[n]);
        }
    }

    float* outb = out + (((size_t)b * NN) + (size_t)ntile * 8) * DD;
#pragma unroll
    for (int n = 0; n < 8; ++n) outb[(size_t)n * DD + tid] = acc[n];
}

extern "C" void kernel_launch(void* const* d_in, const int* in_sizes, int n_in,
                              void* d_out, int out_size, void* d_ws, size_t ws_size,
                              hipStream_t stream) {
    const float* doc     = (const float*)d_in[0];  // (B,S,D)
    const float* mapping = (const float*)d_in[1];  // (B,N,S)
    // d_in[2] = nodes_len (unused)
    const float* W1    = (const float*)d_in[3];    // (D,D)
    const float* b1    = (const float*)d_in[4];    // (D)
    const float* gamma = (const float*)d_in[5];    // (D)
    const float* beta  = (const float*)d_in[6];    // (D)
    const float* W2    = (const float*)d_in[7];    // (D,1)
    const float* b2    = (const float*)d_in[8];    // (1)
    float* out = (float*)d_out;                    // (B,N,D)

    char* base = (char*)d_ws;
    size_t off = 0;
    float* scores = (float*)(base + off); off += (size_t)BB * SS * 4;               // 32 KiB
    float* hbuf   = (float*)(base + off); off += (size_t)BB * SS * DD * 4;          // 8 MiB
    unsigned short* doc_hi = (unsigned short*)(base + off); off += (size_t)BB * SS * DD * 2;  // 4 MiB
    unsigned short* doc_lo = (unsigned short*)(base + off); off += (size_t)BB * SS * DD * 2;  // 4 MiB
    unsigned short* w1t_hi = (unsigned short*)(base + off); off += (size_t)DD * DD * 2;       // 128 KiB
    unsigned short* w1t_lo = (unsigned short*)(base + off); off += (size_t)DD * DD * 2;       // 128 KiB
    float* w      = (float*)(base + off); off += (size_t)BB * NN * SS * 4;          // 4 MiB
    float* part   = (float*)(base + off); off += (size_t)BB * 8 * PSC * PNT * DD * 4; // 16 MiB
    const size_t need = off;

    if (ws_size >= need) {
        split_doc_kernel<<<512, 256, 0, stream>>>(doc, doc_hi, doc_lo);
        split_w1t_kernel<<<16, 256, 0, stream>>>(W1, w1t_hi, w1t_lo);
        scorer_mfma_kernel<<<512, 256, 0, stream>>>(doc_hi, doc_lo, w1t_hi, w1t_lo, hbuf);
        combine_kernel<<<512, 256, 0, stream>>>(hbuf, b1, gamma, beta, W2, b2, scores);
        statsw_kernel<<<256, 256, 0, stream>>>(mapping, scores, w);
        pool16_kernel<<<BB * (NN / PNT) * PSC, 256, 0, stream>>>(doc, w, part);
        reduce16_kernel<<<(BB * NN * DD) / 256, 256, 0, stream>>>(part, out);
    } else {
        float* mx   = scores + BB * SS;
        float* invz = mx + BB * NN;
        scorer_kernel<<<BB * SS / 16, 256, 0, stream>>>(doc, W1, b1, gamma, beta, W2, b2, scores);
        stats_kernel<<<(BB * NN) / 4, 256, 0, stream>>>(mapping, scores, mx, invz);
        pool_direct_kernel<<<BB * 16, 256, 0, stream>>>(doc, mapping, scores, mx, invz, out);
    }
}

// Round 10
// 69.455 us; speedup vs baseline: 1.0911x; 1.0911x over previous
//
#include <hip/hip_runtime.h>
#include <hip/hip_bf16.h>
#include <math.h>

#define DD 256      // feature dim
#define SS 1024     // seq len
#define BB 8        // batch
#define NN 128      // nodes
#define KC 64       // k-chunk for fallback scorer
#define PNT 16      // nodes per pool block
#define PSC 16      // S-chunks in pool
#define PSCH (SS/PSC)  // 64

typedef __attribute__((ext_vector_type(8))) short short8;
typedef __attribute__((ext_vector_type(4))) float f32x4;

__device__ __forceinline__ unsigned short f2bf(float x) {
    unsigned u = __builtin_bit_cast(unsigned, x);
    u += 0x7fffu + ((u >> 16) & 1u);          // round-to-nearest-even
    return (unsigned short)(u >> 16);
}
__device__ __forceinline__ float bf2f(unsigned short h) {
    return __builtin_bit_cast(float, (unsigned)h << 16);
}

// ============ Kernel 0: W1 -> W1T hi/lo (transposed, 64x64 LDS tiles) ============
// (r9 verbatim, PASSED)
__global__ __launch_bounds__(256) void split_w1t_kernel(
    const float* __restrict__ W1,
    unsigned short* __restrict__ w1t_hi, unsigned short* __restrict__ w1t_lo)
{
    __shared__ float tl[64][65];
    const int tid = threadIdx.x;
    const int k0 = (blockIdx.x >> 2) * 64, n0 = (blockIdx.x & 3) * 64;
#pragma unroll
    for (int i = 0; i < 16; ++i) {
        const int idx = i * 256 + tid;
        const int r = idx >> 6, c = idx & 63;
        tl[r][c] = W1[(size_t)(k0 + r) * DD + n0 + c];
    }
    __syncthreads();
#pragma unroll
    for (int i = 0; i < 16; ++i) {
        const int idx = i * 256 + tid;
        const int nl = idx >> 6, kl = idx & 63;
        const float v = tl[kl][nl];
        const unsigned short h = f2bf(v);
        const size_t o = (size_t)(n0 + nl) * DD + k0 + kl;
        w1t_hi[o] = h;
        w1t_lo[o] = f2bf(v - bf2f(h));
    }
}

// ============ Kernel 1: fused MFMA scorer: h=doc@W1+b1, LN, GELU, @W2 -> scores ============
// Block = 16 tokens x 256 cols. 4 waves; wave owns 64-col slice (n0 = 64*wave).
// A (doc): f32 loaded coalesced per lane, split to bf16 hi/lo IN-REGISTER.
// B (W1T): pre-split bf16 hi/lo from global (same pattern as r9, PASSED).
// MFMA: split-bf16 x3 (hi*hi + hi*lo + lo*hi). C/D: col=lane&15, row=(lane>>4)*4+reg.
// Epilogue: per-token LN via 16-lane shfl groups + cross-wave LDS reduce; GELU(erf); W2 dot.
__global__ __launch_bounds__(256) void scorer_mfma_fused(
    const float* __restrict__ doc,
    const unsigned short* __restrict__ w1t_hi, const unsigned short* __restrict__ w1t_lo,
    const float* __restrict__ b1, const float* __restrict__ gamma,
    const float* __restrict__ beta, const float* __restrict__ W2,
    const float* __restrict__ b2, float* __restrict__ scores)
{
    const int tid  = threadIdx.x;
    const int wave = tid >> 6, lane = tid & 63;
    const int l15  = lane & 15, kg = lane >> 4;
    const int t0   = blockIdx.x * 16;     // 16 tokens per block
    const int n0   = wave * 64;           // wave's col slice

    const f32x4 z = {0.f, 0.f, 0.f, 0.f};
    f32x4 acc[4] = {z, z, z, z};          // 4 ntiles of 16 cols

    const float* arow = doc + (size_t)(t0 + l15) * DD;

#pragma unroll 2
    for (int ks = 0; ks < 8; ++ks) {
        const int k = ks * 32 + kg * 8;
        // A-frag: 8 contiguous f32 -> bf16 hi/lo in-register
        const float4 xa = *reinterpret_cast<const float4*>(arow + k);
        const float4 xb = *reinterpret_cast<const float4*>(arow + k + 4);
        short8 ah, al;
        {
            unsigned short h;
            h = f2bf(xa.x); ah[0] = (short)h; al[0] = (short)f2bf(xa.x - bf2f(h));
            h = f2bf(xa.y); ah[1] = (short)h; al[1] = (short)f2bf(xa.y - bf2f(h));
            h = f2bf(xa.z); ah[2] = (short)h; al[2] = (short)f2bf(xa.z - bf2f(h));
            h = f2bf(xa.w); ah[3] = (short)h; al[3] = (short)f2bf(xa.w - bf2f(h));
            h = f2bf(xb.x); ah[4] = (short)h; al[4] = (short)f2bf(xb.x - bf2f(h));
            h = f2bf(xb.y); ah[5] = (short)h; al[5] = (short)f2bf(xb.y - bf2f(h));
            h = f2bf(xb.z); ah[6] = (short)h; al[6] = (short)f2bf(xb.z - bf2f(h));
            h = f2bf(xb.w); ah[7] = (short)h; al[7] = (short)f2bf(xb.w - bf2f(h));
        }
#pragma unroll
        for (int nt = 0; nt < 4; ++nt) {
            const size_t brow = (size_t)(n0 + nt * 16 + l15) * DD + k;
            const short8 bh = *reinterpret_cast<const short8*>(w1t_hi + brow);
            const short8 bl = *reinterpret_cast<const short8*>(w1t_lo + brow);
            acc[nt] = __builtin_amdgcn_mfma_f32_16x16x32_bf16(ah, bh, acc[nt], 0, 0, 0);
            acc[nt] = __builtin_amdgcn_mfma_f32_16x16x32_bf16(ah, bl, acc[nt], 0, 0, 0);
            acc[nt] = __builtin_amdgcn_mfma_f32_16x16x32_bf16(al, bh, acc[nt], 0, 0, 0);
        }
    }

    // per-lane column params (col = n0 + nt*16 + l15)
    float b1v[4], gmv[4], bev[4], w2v[4];
#pragma unroll
    for (int nt = 0; nt < 4; ++nt) {
        const int col = n0 + nt * 16 + l15;
        b1v[nt] = b1[col]; gmv[nt] = gamma[col];
        bev[nt] = beta[col]; w2v[nt] = W2[col];
    }

    __shared__ float s1w[4][16], s2w[4][16], scw[4][16];

    // bias add + per-token partial sums (wave covers 64 of 256 cols)
#pragma unroll
    for (int r = 0; r < 4; ++r) {
        float ls1 = 0.f, ls2 = 0.f;
#pragma unroll
        for (int nt = 0; nt < 4; ++nt) {
            const float v = acc[nt][r] + b1v[nt];
            acc[nt][r] = v;
            ls1 += v;
            ls2 += v * v;
        }
        // reduce across the 16 lanes sharing kg (token = kg*4 + r)
#pragma unroll
        for (int off = 1; off < 16; off <<= 1) {
            ls1 += __shfl_xor(ls1, off, 64);
            ls2 += __shfl_xor(ls2, off, 64);
        }
        if (l15 == 0) {
            s1w[wave][kg * 4 + r] = ls1;
            s2w[wave][kg * 4 + r] = ls2;
        }
    }
    __syncthreads();

    // per-token mean/inv (sum across 4 waves)
    float meanv[4], invv[4];
#pragma unroll
    for (int r = 0; r < 4; ++r) {
        const int t = kg * 4 + r;
        const float s1 = s1w[0][t] + s1w[1][t] + s1w[2][t] + s1w[3][t];
        const float s2 = s2w[0][t] + s2w[1][t] + s2w[2][t] + s2w[3][t];
        const float mean = s1 * (1.f / DD);
        const float var  = s2 * (1.f / DD) - mean * mean;
        meanv[r] = mean;
        invv[r]  = rsqrtf(var + 1e-5f);
    }

    // GELU + W2 partial dot
    const float kq = 0.70710678118654752f;
#pragma unroll
    for (int r = 0; r < 4; ++r) {
        float p = 0.f;
#pragma unroll
        for (int nt = 0; nt < 4; ++nt) {
            const float nx = (acc[nt][r] - meanv[r]) * invv[r] * gmv[nt] + bev[nt];
            const float g  = 0.5f * nx * (1.f + erff(nx * kq));
            p = fmaf(g, w2v[nt], p);
        }
#pragma unroll
        for (int off = 1; off < 16; off <<= 1) p += __shfl_xor(p, off, 64);
        if (l15 == 0) scw[wave][kg * 4 + r] = p;
    }
    __syncthreads();

    if (tid < 16)
        scores[t0 + tid] = scw[0][tid] + scw[1][tid] + scw[2][tid] + scw[3][tid] + b2[0];
}

// ====== Kernel 2 (r7/r9 verbatim, PASSED): masked softmax -> float weights w ======
__global__ __launch_bounds__(256) void statsw_kernel(
    const float* __restrict__ mapping, const float* __restrict__ scores,
    float* __restrict__ w)
{
    __shared__ float sc_s[SS];
    const int tid  = threadIdx.x, lane = tid & 63;
    const int wave = __builtin_amdgcn_readfirstlane(tid >> 6);
    const int g0   = blockIdx.x * 4;
    const int b    = g0 >> 7;

    reinterpret_cast<float4*>(sc_s)[tid] =
        reinterpret_cast<const float4*>(scores + (size_t)b * SS)[tid];
    __syncthreads();

    const int g = g0 + wave;
    const float4* mrow4 = reinterpret_cast<const float4*>(mapping + (size_t)g * SS);
    const float4* sc4   = reinterpret_cast<const float4*>(sc_s);

    float4 mv[4], sv[4];
    float mx = -INFINITY;
#pragma unroll
    for (int q = 0; q < 4; ++q) {
        mv[q] = mrow4[lane + (q << 6)];
        sv[q] = sc4[lane + (q << 6)];
        if (mv[q].x > 0.5f) mx = fmaxf(mx, sv[q].x);
        if (mv[q].y > 0.5f) mx = fmaxf(mx, sv[q].y);
        if (mv[q].z > 0.5f) mx = fmaxf(mx, sv[q].z);
        if (mv[q].w > 0.5f) mx = fmaxf(mx, sv[q].w);
    }
#pragma unroll
    for (int off = 32; off > 0; off >>= 1) mx = fmaxf(mx, __shfl_xor(mx, off, 64));
    float z = 0.f;
    float4 ev[4];
#pragma unroll
    for (int q = 0; q < 4; ++q) {
        ev[q].x = (mv[q].x > 0.5f) ? __expf(sv[q].x - mx) : 0.f;
        ev[q].y = (mv[q].y > 0.5f) ? __expf(sv[q].y - mx) : 0.f;
        ev[q].z = (mv[q].z > 0.5f) ? __expf(sv[q].z - mx) : 0.f;
        ev[q].w = (mv[q].w > 0.5f) ? __expf(sv[q].w - mx) : 0.f;
        z += ev[q].x + ev[q].y + ev[q].z + ev[q].w;
    }
#pragma unroll
    for (int off = 32; off > 0; off >>= 1) z += __shfl_xor(z, off, 64);
    const float invz = (z > 0.f) ? (1.f / z) : 0.f;

    float4* wrow4 = reinterpret_cast<float4*>(w + (size_t)g * SS);
#pragma unroll
    for (int q = 0; q < 4; ++q) {
        float4 e;
        e.x = ev[q].x * invz; e.y = ev[q].y * invz;
        e.z = ev[q].z * invz; e.w = ev[q].w * invz;
        wrow4[lane + (q << 6)] = e;
    }
}

// ====== Kernel 3 (r7/r9 verbatim, PASSED): pooled partials, scalar-load weights ======
__global__ __launch_bounds__(256) void pool16_kernel(
    const float* __restrict__ doc, const float* __restrict__ w,
    float* __restrict__ part)
{
    const int blk = blockIdx.x;
    const int c   = blk & (PSC - 1);
    const int nt  = (blk >> 4) & 7;
    const int b   = blk >> 7;
    const int s0  = c * PSCH;
    const int d   = threadIdx.x;

    float acc[PNT];
#pragma unroll
    for (int n = 0; n < PNT; ++n) acc[n] = 0.f;

    const float* docb = doc + ((size_t)b * SS + s0) * DD;
    const float* wb   = w + ((size_t)(b * NN + nt * PNT)) * SS + s0;

#pragma unroll 1
    for (int sb = 0; sb < PSCH; sb += 16) {
        float dr[16];
#pragma unroll
        for (int j = 0; j < 16; ++j)
            dr[j] = docb[(size_t)(sb + j) * DD + d];

#pragma unroll
        for (int n = 0; n < PNT; ++n) {
            const float* wn = wb + (size_t)n * SS + sb;
            const float4 w0 = *reinterpret_cast<const float4*>(wn);
            const float4 w1 = *reinterpret_cast<const float4*>(wn + 4);
            const float4 w2 = *reinterpret_cast<const float4*>(wn + 8);
            const float4 w3 = *reinterpret_cast<const float4*>(wn + 12);
            float a = acc[n];
            a = fmaf(w0.x, dr[0],  a);
            a = fmaf(w0.y, dr[1],  a);
            a = fmaf(w0.z, dr[2],  a);
            a = fmaf(w0.w, dr[3],  a);
            a = fmaf(w1.x, dr[4],  a);
            a = fmaf(w1.y, dr[5],  a);
            a = fmaf(w1.z, dr[6],  a);
            a = fmaf(w1.w, dr[7],  a);
            a = fmaf(w2.x, dr[8],  a);
            a = fmaf(w2.y, dr[9],  a);
            a = fmaf(w2.z, dr[10], a);
            a = fmaf(w2.w, dr[11], a);
            a = fmaf(w3.x, dr[12], a);
            a = fmaf(w3.y, dr[13], a);
            a = fmaf(w3.z, dr[14], a);
            a = fmaf(w3.w, dr[15], a);
            acc[n] = a;
        }
    }

    float* p = part + (size_t)blk * (PNT * DD);
#pragma unroll
    for (int n = 0; n < PNT; ++n) p[(size_t)n * DD + d] = acc[n];
}

// ---------------- Kernel 4 (r7/r9 verbatim, PASSED): reduce PSC partials ----------------
__global__ __launch_bounds__(256) void reduce16_kernel(
    const float* __restrict__ part, float* __restrict__ out)
{
    const int o = blockIdx.x * 256 + threadIdx.x;
    const int d = o & 255;
    const int g = o >> 8;
    const int b = g >> 7;
    const int n = g & 127;
    const int nt = n >> 4, nl = n & 15;
    const size_t base = ((size_t)(b * 128 + nt * 16)) * (PNT * DD)
                      + (size_t)nl * DD + d;
    float s = 0.f;
#pragma unroll
    for (int c = 0; c < PSC; ++c) s += part[base + (size_t)c * (PNT * DD)];
    out[o] = s;
}

// ================= Fallback path (tiny ws): r5 verified kernels =================
__global__ __launch_bounds__(256) void scorer_kernel(
    const float* __restrict__ doc, const float* __restrict__ W1,
    const float* __restrict__ b1, const float* __restrict__ gamma,
    const float* __restrict__ beta, const float* __restrict__ W2,
    const float* __restrict__ b2, float* __restrict__ scores)
{
    __shared__ float xs[16][DD];
    __shared__ float w1s[KC][DD];

    const int tid  = threadIdx.x;
    const int wave = tid >> 6, lane = tid & 63;
    const int t0   = blockIdx.x * 16;
    const int c0   = lane * 4;

    {
        const float4* src = reinterpret_cast<const float4*>(doc + (size_t)t0 * DD);
        float4* dst = reinterpret_cast<float4*>(&xs[0][0]);
#pragma unroll
        for (int r = 0; r < 4; ++r) dst[tid + 256 * r] = src[tid + 256 * r];
    }

    float4 acc[4];
    {
        const float4 bv = *reinterpret_cast<const float4*>(b1 + c0);
#pragma unroll
        for (int t = 0; t < 4; ++t) acc[t] = bv;
    }
    const float* xw = &xs[wave * 4][0];

    for (int kc = 0; kc < DD / KC; ++kc) {
        __syncthreads();
        {
            const float4* wsrc = reinterpret_cast<const float4*>(W1 + (size_t)kc * KC * DD);
            float4* wdst = reinterpret_cast<float4*>(&w1s[0][0]);
#pragma unroll
            for (int r = 0; r < 16; ++r) wdst[tid + 256 * r] = wsrc[tid + 256 * r];
        }
        __syncthreads();
#pragma unroll 4
        for (int k4 = 0; k4 < KC / 4; ++k4) {
            const int kb = k4 * 4;
            const float4 w0 = *reinterpret_cast<const float4*>(&w1s[kb + 0][c0]);
            const float4 w1 = *reinterpret_cast<const float4*>(&w1s[kb + 1][c0]);
            const float4 w2 = *reinterpret_cast<const float4*>(&w1s[kb + 2][c0]);
            const float4 w3 = *reinterpret_cast<const float4*>(&w1s[kb + 3][c0]);
#pragma unroll
            for (int t = 0; t < 4; ++t) {
                const float4 xv = *reinterpret_cast<const float4*>(xw + (size_t)t * DD + kc * KC + kb);
                acc[t].x = fmaf(xv.x, w0.x, acc[t].x);
                acc[t].y = fmaf(xv.x, w0.y, acc[t].y);
                acc[t].z = fmaf(xv.x, w0.z, acc[t].z);
                acc[t].w = fmaf(xv.x, w0.w, acc[t].w);
                acc[t].x = fmaf(xv.y, w1.x, acc[t].x);
                acc[t].y = fmaf(xv.y, w1.y, acc[t].y);
                acc[t].z = fmaf(xv.y, w1.z, acc[t].z);
                acc[t].w = fmaf(xv.y, w1.w, acc[t].w);
                acc[t].x = fmaf(xv.z, w2.x, acc[t].x);
                acc[t].y = fmaf(xv.z, w2.y, acc[t].y);
                acc[t].z = fmaf(xv.z, w2.z, acc[t].z);
                acc[t].w = fmaf(xv.z, w2.w, acc[t].w);
                acc[t].x = fmaf(xv.w, w3.x, acc[t].x);
                acc[t].y = fmaf(xv.w, w3.y, acc[t].y);
                acc[t].z = fmaf(xv.w, w3.z, acc[t].z);
                acc[t].w = fmaf(xv.w, w3.w, acc[t].w);
            }
        }
    }

    const float4 gm = *reinterpret_cast<const float4*>(gamma + c0);
    const float4 be = *reinterpret_cast<const float4*>(beta + c0);
    const float4 w2v = *reinterpret_cast<const float4*>(W2 + c0);
    const float b2v = b2[0];

#pragma unroll
    for (int t = 0; t < 4; ++t) {
        float s1 = acc[t].x + acc[t].y + acc[t].z + acc[t].w;
        float s2 = acc[t].x * acc[t].x + acc[t].y * acc[t].y
                 + acc[t].z * acc[t].z + acc[t].w * acc[t].w;
#pragma unroll
        for (int off = 32; off > 0; off >>= 1) {
            s1 += __shfl_xor(s1, off, 64);
            s2 += __shfl_xor(s2, off, 64);
        }
        const float mean = s1 * (1.f / DD);
        const float var  = s2 * (1.f / DD) - mean * mean;
        const float inv  = rsqrtf(var + 1e-5f);
        float n0 = (acc[t].x - mean) * inv * gm.x + be.x;
        float n1 = (acc[t].y - mean) * inv * gm.y + be.y;
        float n2 = (acc[t].z - mean) * inv * gm.z + be.z;
        float n3 = (acc[t].w - mean) * inv * gm.w + be.w;
        const float kq = 0.70710678118654752f;
        float g0 = 0.5f * n0 * (1.f + erff(n0 * kq));
        float g1 = 0.5f * n1 * (1.f + erff(n1 * kq));
        float g2 = 0.5f * n2 * (1.f + erff(n2 * kq));
        float g3 = 0.5f * n3 * (1.f + erff(n3 * kq));
        float sc = g0 * w2v.x + g1 * w2v.y + g2 * w2v.z + g3 * w2v.w;
#pragma unroll
        for (int off = 32; off > 0; off >>= 1) sc += __shfl_xor(sc, off, 64);
        if (lane == 0) scores[t0 + wave * 4 + t] = sc + b2v;
    }
}

__global__ __launch_bounds__(256) void stats_kernel(
    const float* __restrict__ mapping, const float* __restrict__ scores,
    float* __restrict__ mx_out, float* __restrict__ invz_out)
{
    __shared__ float sc_s[SS];
    const int tid = threadIdx.x, wave = tid >> 6, lane = tid & 63;
    const int g0 = blockIdx.x * 4;
    const int b  = g0 >> 7;

    reinterpret_cast<float4*>(sc_s)[tid] =
        reinterpret_cast<const float4*>(scores + (size_t)b * SS)[tid];
    __syncthreads();

    const int g = g0 + wave;
    const float4* mrow4 = reinterpret_cast<const float4*>(mapping + (size_t)g * SS);
    const float4* sc4   = reinterpret_cast<const float4*>(sc_s);

    float4 mv[4], sv[4];
    float mx = -INFINITY;
#pragma unroll
    for (int q = 0; q < 4; ++q) {
        mv[q] = mrow4[lane + (q << 6)];
        sv[q] = sc4[lane + (q << 6)];
        if (mv[q].x > 0.5f) mx = fmaxf(mx, sv[q].x);
        if (mv[q].y > 0.5f) mx = fmaxf(mx, sv[q].y);
        if (mv[q].z > 0.5f) mx = fmaxf(mx, sv[q].z);
        if (mv[q].w > 0.5f) mx = fmaxf(mx, sv[q].w);
    }
#pragma unroll
    for (int off = 32; off > 0; off >>= 1) mx = fmaxf(mx, __shfl_xor(mx, off, 64));
    float z = 0.f;
#pragma unroll
    for (int q = 0; q < 4; ++q) {
        if (mv[q].x > 0.5f) z += __expf(sv[q].x - mx);
        if (mv[q].y > 0.5f) z += __expf(sv[q].y - mx);
        if (mv[q].z > 0.5f) z += __expf(sv[q].z - mx);
        if (mv[q].w > 0.5f) z += __expf(sv[q].w - mx);
    }
#pragma unroll
    for (int off = 32; off > 0; off >>= 1) z += __shfl_xor(z, off, 64);
    if (lane == 0) {
        mx_out[g]   = mx;
        invz_out[g] = (z > 0.f) ? (1.f / z) : 0.f;
    }
}

__global__ __launch_bounds__(256) void pool_direct_kernel(
    const float* __restrict__ doc, const float* __restrict__ mapping,
    const float* __restrict__ scores, const float* __restrict__ mx_in,
    const float* __restrict__ invz_in, float* __restrict__ out)
{
    __shared__ float w_lds[8][SS];

    const int bt    = blockIdx.x;
    const int ntile = bt & 15;
    const int b     = bt >> 4;
    const int tid = threadIdx.x, wave = tid >> 6, lane = tid & 63;

    {
        const int nl = wave * 2 + (lane >> 5);
        const int g  = b * NN + ntile * 8 + nl;
        const float mx   = mx_in[g];
        const float invz = invz_in[g];
        const float4* mrow4 = reinterpret_cast<const float4*>(mapping + (size_t)g * SS);
        const float4* srow4 = reinterpret_cast<const float4*>(scores + (size_t)b * SS);
        float4* wrow4 = reinterpret_cast<float4*>(&w_lds[nl][0]);
        const int idx0 = lane & 31;
#pragma unroll
        for (int q = 0; q < SS / 128; ++q) {
            const int idx = idx0 + 32 * q;
            const float4 mp = mrow4[idx];
            const float4 sv = srow4[idx];
            float4 e;
            e.x = (mp.x > 0.5f) ? __expf(sv.x - mx) * invz : 0.f;
            e.y = (mp.y > 0.5f) ? __expf(sv.y - mx) * invz : 0.f;
            e.z = (mp.z > 0.5f) ? __expf(sv.z - mx) * invz : 0.f;
            e.w = (mp.w > 0.5f) ? __expf(sv.w - mx) * invz : 0.f;
            wrow4[idx] = e;
        }
    }
    __syncthreads();

    float acc[8];
#pragma unroll
    for (int n = 0; n < 8; ++n) acc[n] = 0.f;
    const float* docb = doc + (size_t)b * SS * DD;

    for (int s4 = 0; s4 < SS; s4 += 4) {
        const float d0 = docb[(size_t)(s4 + 0) * DD + tid];
        const float d1 = docb[(size_t)(s4 + 1) * DD + tid];
        const float d2 = docb[(size_t)(s4 + 2) * DD + tid];
        const float d3 = docb[(size_t)(s4 + 3) * DD + tid];
#pragma unroll
        for (int n = 0; n < 8; ++n) {
            const float4 wv = *reinterpret_cast<const float4*>(&w_lds[n][s4]);
            acc[n] = fmaf(wv.x, d0, acc[n]);
            acc[n] = fmaf(wv.y, d1, acc[n]);
            acc[n] = fmaf(wv.z, d2, acc[n]);
            acc[n] = fmaf(wv.w, d3, acc[n]);
        }
    }

    float* outb = out + (((size_t)b * NN) + (size_t)ntile * 8) * DD;
#pragma unroll
    for (int n = 0; n < 8; ++n) outb[(size_t)n * DD + tid] = acc[n];
}

extern "C" void kernel_launch(void* const* d_in, const int* in_sizes, int n_in,
                              void* d_out, int out_size, void* d_ws, size_t ws_size,
                              hipStream_t stream) {
    const float* doc     = (const float*)d_in[0];  // (B,S,D)
    const float* mapping = (const float*)d_in[1];  // (B,N,S)
    // d_in[2] = nodes_len (unused)
    const float* W1    = (const float*)d_in[3];    // (D,D)
    const float* b1    = (const float*)d_in[4];    // (D)
    const float* gamma = (const float*)d_in[5];    // (D)
    const float* beta  = (const float*)d_in[6];    // (D)
    const float* W2    = (const float*)d_in[7];    // (D,1)
    const float* b2    = (const float*)d_in[8];    // (1)
    float* out = (float*)d_out;                    // (B,N,D)

    char* base = (char*)d_ws;
    size_t off = 0;
    float* scores = (float*)(base + off); off += (size_t)BB * SS * 4;                   // 32 KiB
    unsigned short* w1t_hi = (unsigned short*)(base + off); off += (size_t)DD * DD * 2; // 128 KiB
    unsigned short* w1t_lo = (unsigned short*)(base + off); off += (size_t)DD * DD * 2; // 128 KiB
    float* w      = (float*)(base + off); off += (size_t)BB * NN * SS * 4;              // 4 MiB
    float* part   = (float*)(base + off); off += (size_t)BB * 8 * PSC * PNT * DD * 4;   // 16 MiB
    const size_t need = off;

    if (ws_size >= need) {
        split_w1t_kernel<<<16, 256, 0, stream>>>(W1, w1t_hi, w1t_lo);
        scorer_mfma_fused<<<BB * SS / 16, 256, 0, stream>>>(doc, w1t_hi, w1t_lo,
                                                            b1, gamma, beta, W2, b2, scores);
        statsw_kernel<<<256, 256, 0, stream>>>(mapping, scores, w);
        pool16_kernel<<<BB * (NN / PNT) * PSC, 256, 0, stream>>>(doc, w, part);
        reduce16_kernel<<<(BB * NN * DD) / 256, 256, 0, stream>>>(part, out);
    } else {
        float* mx   = scores + BB * SS;
        float* invz = mx + BB * NN;
        scorer_kernel<<<BB * SS / 16, 256, 0, stream>>>(doc, W1, b1, gamma, beta, W2, b2, scores);
        stats_kernel<<<(BB * NN) / 4, 256, 0, stream>>>(mapping, scores, mx, invz);
        pool_direct_kernel<<<BB * 16, 256, 0, stream>>>(doc, mapping, scores, mx, invz, out);
    }
}